// Round 8
// baseline (943.447 us; speedup 1.0000x reference)
//
#include <hip/hip_runtime.h>
#include <cstdint>
#include <cstddef>

// dec: [16, 3999, 512] fp32, wgt: [16, 512] fp32, out: [16, 32000] fp32
//   est[f][w] = dot(dec[f], wgt[w]);  out[8g+i] = est[g][i] + est[g-1][8+i]
//
// R14 = coalesced lane remap (R12/R13 concept) sized to genuinely fit the
// 64-VGPR / 8-waves-per-EU budget the compiler insists on:
//   - 1024-thread blocks, 64 x 16-lane groups, ONE slot per group
//     -> acc[16] (16 VGPR) + xv[2] dbuf (8) + wv[2] (8) + addr (~12) ~= 50.
//   - R13 failed here: acc[2][16]+wv[4] ~= 80 static vs the 64 cap the
//     compiler picked to match LDS-allowed occupancy -> 964 MB of spill
//     stores (output is 2 MB) and 660 us. Spill gate this round:
//     WRITE_SIZE must be ~2 MB.
// Lane remap: kappa=lane&15 reads a 16 B stripe; each 16-lane group covers
// 256 B contiguous of one frame -> every wave-instr = 16 fully-consumed
// cache lines (vs 64 distinct lines for the lane=frame scatter, which
// plateaus at ~2.2 TB/s). Weights from LDS (kappa-dependent; 2-way bank
// alias only = free); kappa-split partials reduced by 4-step __shfl_xor
// butterfly inside each 16-lane group. Zero main-loop barriers.

#define NBC     16
#define FRAMES  3999
#define EE      512
#define TOUT    32000
#define NGROUP  4000
#define GPB     63      // output groups per block (64 frame-slots)
#define RSTR    65      // red row stride (pad)

__global__ __launch_bounds__(1024, 8) void decoder_kernel(
    const float* __restrict__ dec,
    const float* __restrict__ wgt,
    float* __restrict__ out)
{
    __shared__ __align__(16) float wl[16 * EE];   // 32 KB weights
    __shared__ float red[16 * RSTR];              // est[w][slot], padded

    const int tid   = threadIdx.x;
    const int bc    = blockIdx.y;        // 0..15
    const int chunk = blockIdx.x;        // 0..63
    const int g0    = chunk * GPB;

    const int kappa = tid & 15;          // k-phase within frame
    const int slot  = tid >> 4;          // 0..63 (frame slot; 1 per group)

    // ---- stage weights into LDS (coalesced, once) ----
    {
        const float4* ws = (const float4*)wgt;
        float4*       wd = (float4*)wl;
        wd[tid]        = ws[tid];
        wd[tid + 1024] = ws[tid + 1024];
    }
    __syncthreads();

    // ---- this group's frame ----
    const int f = g0 - 1 + slot;
    const float msk = (f >= 0 && f < FRAMES) ? 1.0f : 0.0f;
    const int fr = min(max(f, 0), FRAMES - 1);
    const float* xp = dec + ((size_t)bc * FRAMES + fr) * EE + kappa * 4;

    float acc[16];
    #pragma unroll
    for (int w = 0; w < 16; ++w) acc[w] = 0.f;

    // ---- main loop: u = k-block of 64 floats; 2-deep prefetch; no barriers
    float4 xv[2];
    xv[0] = *(const float4*)xp;

    #pragma unroll
    for (int u = 0; u < 8; ++u) {
        const int cur = u & 1;           // compile-time after unroll
        if (u < 7)
            xv[cur ^ 1] = *(const float4*)(xp + (u + 1) * 64);

        #pragma unroll
        for (int wq = 0; wq < 8; ++wq) {
            float4 wv0 = *(const float4*)(wl + (wq * 2 + 0) * EE + u * 64 + kappa * 4);
            float4 wv1 = *(const float4*)(wl + (wq * 2 + 1) * EE + u * 64 + kappa * 4);
            acc[wq * 2 + 0] += xv[cur].x * wv0.x + xv[cur].y * wv0.y
                             + xv[cur].z * wv0.z + xv[cur].w * wv0.w;
            acc[wq * 2 + 1] += xv[cur].x * wv1.x + xv[cur].y * wv1.y
                             + xv[cur].z * wv1.z + xv[cur].w * wv1.w;
        }
    }

    // ---- reduce over the 16 kappa-lanes; lane kappa==w writes est ----
    #pragma unroll
    for (int w = 0; w < 16; ++w) {
        float v = acc[w];
        v += __shfl_xor(v, 1);
        v += __shfl_xor(v, 2);
        v += __shfl_xor(v, 4);
        v += __shfl_xor(v, 8);
        if (kappa == w)
            red[w * RSTR + slot] = v * msk;
    }
    __syncthreads();

    // ---- fused overlap-add: 504 outputs ----
    if (tid < GPB * 8) {
        const int j = tid >> 3;          // group offset in block, 0..62
        const int i = tid & 7;           // sample within group
        const int g = g0 + j;
        if (g < NGROUP)
            out[(size_t)bc * TOUT + g * 8 + i]
                = red[i * RSTR + (j + 1)]        // est[g][i]
                + red[(8 + i) * RSTR + j];       // est[g-1][8+i]
    }
}

extern "C" void kernel_launch(void* const* d_in, const int* in_sizes, int n_in,
                              void* d_out, int out_size, void* d_ws, size_t ws_size,
                              hipStream_t stream) {
    const float* dec = (const float*)d_in[0];   // [8,2,3999,512] fp32
    const float* wgt = (const float*)d_in[1];   // [16,512] fp32
    float* out = (float*)d_out;                 // [8,2,32000] fp32

    decoder_kernel<<<dim3(64, 16), dim3(1024), 0, stream>>>(dec, wgt, out);
}

// Round 9
// 855.428 us; speedup vs baseline: 1.1029x; 1.1029x over previous
//
#include <hip/hip_runtime.h>
#include <cstdint>
#include <cstddef>

// dec: [16, 3999, 512] fp32, wgt: [16, 512] fp32, out: [16, 32000] fp32
//   est[f][w] = dot(dec[f], wgt[w]);  out[8g+i] = est[g][i] + est[g-1][8+i]
//
// R15 = kappa-coalesced remap (R12-R14 concept) in the ONLY envelope that
// has never spilled (R6: 256 threads, launch_bounds(256,4), VGPR=48).
//   R12/R13/R14 all spilled (505 MB / 964 MB / 1.9 GB scratch writes) --
//   the aggressive launch_bounds (512,4)/(1024,8) drove the allocator to
//   degenerate VGPR caps (64/32). Yet R14 sustained 3.6 TB/s even while
//   scratch-thrashing -> the coalesced pattern itself is sound.
// Structure: kappa = tid&15 reads a 16 B k-stripe; each 16-lane group
// covers 256 B contiguous of ONE frame -> every wave-instruction touches
// 16 fully-consumed cache lines (vs 64 distinct lines for lane=frame).
// One slot per group -> 16 slots / 15 output groups per block, grid 267x16.
// Registers: acc[16] + NAMED float4 double-buffer (xva/xvb, hand-unrolled
// macro steps -- no runtime-indexable arrays) + 2 weight temps ~= 55 VGPR.
// Weights from LDS (kappa-dependent; 16 distinct addrs spanning 256 B =
// 2-way bank alias only = free). Butterfly kappa-reduction; zero main-loop
// barriers. LDS 33 KB -> 4 blocks/CU = 16 waves/CU.

#define NBC     16
#define FRAMES  3999
#define EE      512
#define TOUT    32000
#define NGROUP  4000
#define GPB     15      // output groups per block (16 frame-slots)
#define NCHUNK  267     // ceil(4000/15)
#define RSTR    17      // red row stride (16+1 pad)

__global__ __launch_bounds__(256, 4) void decoder_kernel(
    const float* __restrict__ dec,
    const float* __restrict__ wgt,
    float* __restrict__ out)
{
    __shared__ __align__(16) float wl[16 * EE];   // 32 KB weights
    __shared__ float red[16 * RSTR];              // est[w][slot], padded

    const int tid   = threadIdx.x;
    const int bc    = blockIdx.y;        // 0..15
    const int chunk = blockIdx.x;        // 0..266
    const int g0    = chunk * GPB;

    const int kappa = tid & 15;          // k-phase within frame
    const int slot  = tid >> 4;          // 0..15 (one frame slot per group)

    // ---- stage weights into LDS (coalesced, once) ----
    {
        const float4* ws = (const float4*)wgt;
        float4*       wd = (float4*)wl;
        #pragma unroll
        for (int i = 0; i < 8; ++i)
            wd[tid + 256 * i] = ws[tid + 256 * i];
    }
    __syncthreads();

    // ---- this group's frame ----
    const int f = g0 - 1 + slot;
    const float msk = (f >= 0 && f < FRAMES) ? 1.0f : 0.0f;
    const int fr = min(max(f, 0), FRAMES - 1);
    const float* xp = dec + ((size_t)bc * FRAMES + fr) * EE + kappa * 4;

    float acc[16];
    #pragma unroll
    for (int w = 0; w < 16; ++w) acc[w] = 0.f;

    // ---- main loop: 8 k-blocks of 64 floats; named double-buffer, ----
    // ---- hand-unrolled steps (no runtime-indexed register arrays)  ----
    float4 xva, xvb;

#define FMA_BLOCK(XV, U)                                                     \
    {                                                                        \
        _Pragma("unroll")                                                    \
        for (int wq = 0; wq < 8; ++wq) {                                     \
            const float4 wv0 = *(const float4*)(wl + (wq * 2 + 0) * EE       \
                                                   + (U) * 64 + kappa * 4);  \
            const float4 wv1 = *(const float4*)(wl + (wq * 2 + 1) * EE       \
                                                   + (U) * 64 + kappa * 4);  \
            acc[wq * 2 + 0] += (XV).x * wv0.x + (XV).y * wv0.y               \
                             + (XV).z * wv0.z + (XV).w * wv0.w;              \
            acc[wq * 2 + 1] += (XV).x * wv1.x + (XV).y * wv1.y               \
                             + (XV).z * wv1.z + (XV).w * wv1.w;              \
        }                                                                    \
    }

    xva = *(const float4*)(xp);
    xvb = *(const float4*)(xp + 64);     // 2 lines in flight
    FMA_BLOCK(xva, 0)
    xva = *(const float4*)(xp + 2 * 64);
    FMA_BLOCK(xvb, 1)
    xvb = *(const float4*)(xp + 3 * 64);
    FMA_BLOCK(xva, 2)
    xva = *(const float4*)(xp + 4 * 64);
    FMA_BLOCK(xvb, 3)
    xvb = *(const float4*)(xp + 5 * 64);
    FMA_BLOCK(xva, 4)
    xva = *(const float4*)(xp + 6 * 64);
    FMA_BLOCK(xvb, 5)
    xvb = *(const float4*)(xp + 7 * 64);
    FMA_BLOCK(xva, 6)
    FMA_BLOCK(xvb, 7)
#undef FMA_BLOCK

    // ---- reduce over the 16 kappa-lanes; lane kappa==w writes est ----
    #pragma unroll
    for (int w = 0; w < 16; ++w) {
        float v = acc[w];
        v += __shfl_xor(v, 1);
        v += __shfl_xor(v, 2);
        v += __shfl_xor(v, 4);
        v += __shfl_xor(v, 8);
        if (kappa == w)
            red[w * RSTR + slot] = v * msk;
    }
    __syncthreads();

    // ---- fused overlap-add: 120 outputs ----
    if (tid < GPB * 8) {
        const int j = tid >> 3;          // group offset in block, 0..14
        const int i = tid & 7;           // sample within group
        const int g = g0 + j;
        if (g < NGROUP)
            out[(size_t)bc * TOUT + g * 8 + i]
                = red[i * RSTR + (j + 1)]        // est[g][i]
                + red[(8 + i) * RSTR + j];       // est[g-1][8+i]
    }
}

extern "C" void kernel_launch(void* const* d_in, const int* in_sizes, int n_in,
                              void* d_out, int out_size, void* d_ws, size_t ws_size,
                              hipStream_t stream) {
    const float* dec = (const float*)d_in[0];   // [8,2,3999,512] fp32
    const float* wgt = (const float*)d_in[1];   // [16,512] fp32
    float* out = (float*)d_out;                 // [8,2,32000] fp32

    decoder_kernel<<<dim3(NCHUNK, NBC), dim3(256), 0, stream>>>(dec, wgt, out);
}

// Round 10
// 200.881 us; speedup vs baseline: 4.6966x; 4.2584x over previous
//
#include <hip/hip_runtime.h>
#include <cstdint>
#include <cstddef>

// dec: [16, 3999, 512] fp32, wgt: [16, 512] fp32, out: [16, 32000] fp32
//   est[f][w] = dot(dec[f], wgt[w]);  out[8g+i] = est[g][i] + est[g-1][8+i]
//
// R16: wave-private coalesced staging. Each wave q owns k-quarter
// [q*128,q*128+128) of all 64 frames; per 16-float chunk it stages
// 64 frames x 64 B through REGISTERS into ITS OWN padded LDS region
// (global->reg->ds_write, T14), then reads back lane=frame. Properties:
//  - global side: each wave-instr reads 16 frames x 64 B = 16 FULLY
//    consumed lines (R12-R15 proved this sustains 3.6+ TB/s vs 2.2 for
//    the lane=frame scatter: 64 lines/instr, L1-thrashed).
//  - ZERO main-loop barriers (R8/R11: inter-wave barrier lockstep = 81us).
//    Wave-private buffers; compiler inserts the vmcnt before the
//    ds_write, which sits AFTER the chunk's 256 FMAs -> latency hidden.
//  - LDS frame stride 20 dwords (80 B) -> ds_write AND ds_read <=2-way
//    bank alias = free (gload_lds forbids padding; reg-staging allows it).
//  - register envelope: acc[16]+xg[4]f4+xv ~66 VGPR, 256 thr,
//    launch_bounds(256,4) -- the only envelope that never spilled (R6=48).
//    R12-R15 all spilled (0.5-1.9 GB scratch): spill gate this round is
//    WRITE_SIZE ~2 MB, VGPR 56-100.
//  - weights: wave-uniform scalar loads (R7: cost-neutral; no LDS, no VGPR).
// LDS: xs[4 waves][2 bufs][64 frames][20] = 40 KB -> 4 blocks/CU; red
// (4x16x65 = 16.6 KB) overlays xs after a barrier. 2 barriers total.

#define NBC     16
#define FRAMES  3999
#define EE      512
#define TOUT    32000
#define NGROUP  4000
#define GPB     63      // output groups per block (64 frame-slots)
#define RSTR    65      // red row stride (pad)
#define XSTR    20      // xs frame stride in dwords (80 B; 2-way max alias)
#define BUFSTEP (64 * XSTR)              // dwords per buffer (one wave)

__global__ __launch_bounds__(256, 4) void decoder_kernel(
    const float* __restrict__ dec,
    const float* __restrict__ wgt,
    float* __restrict__ out)
{
    __shared__ __align__(16) float xs[4 * 2 * BUFSTEP];   // 40 KB
    float* red = xs;                                      // 16.6 KB overlay

    const int tid   = threadIdx.x;
    const int bc    = blockIdx.x >> 6;   // 0..15
    const int chunk = blockIdx.x & 63;   // 0..63
    const int g0    = chunk * GPB;

    const int lane = tid & 63;
    const int s    = lane;               // frame slot for compute
    const int q    = __builtin_amdgcn_readfirstlane(tid >> 6);   // 0..3

    const int f = g0 - 1 + s;
    const float vmask = (f >= 0 && f < FRAMES) ? 1.0f : 0.0f;

    const float* decb = dec + (size_t)bc * FRAMES * EE;

    // ---- staging plan: chunk = 64 frames x 16 floats (4 KB/wave).
    // instr i: lane covers frame fi = i*16 + (lane>>2), 16 B word j = lane&3;
    // -> 16 frames x 64 B contiguous = 16 full lines per instruction.
    const float* sp[4];                  // global src (+ c*16 per chunk)
    int          dp[4];                  // LDS dst dword offset (+ buf*BUFSTEP)
    #pragma unroll
    for (int i = 0; i < 4; ++i) {
        const int fi = i * 16 + (lane >> 2);
        const int j  = lane & 3;
        const int fr = min(max(g0 - 1 + fi, 0), FRAMES - 1);
        sp[i] = decb + (size_t)fr * EE + q * 128 + j * 4;
        dp[i] = (q * 2) * BUFSTEP + fi * XSTR + j * 4;
    }
    const int xrb = (q * 2) * BUFSTEP + s * XSTR;   // compute-read base

    // wave-uniform weight base: rows w, this wave's k-quarter
    const float* wq = wgt + q * 128;

    float acc[16];
    #pragma unroll
    for (int w = 0; w < 16; ++w) acc[w] = 0.f;

    // ---- prologue: stage chunk 0 into buf 0 (one exposed vmcnt) ----
    {
        float4 t[4];
        #pragma unroll
        for (int i = 0; i < 4; ++i) t[i] = *(const float4*)(sp[i]);
        #pragma unroll
        for (int i = 0; i < 4; ++i) *(float4*)(xs + dp[i]) = t[i];
    }

    // ---- main loop: 8 chunks of 16 k; wave-private, no barriers ----
    #pragma unroll
    for (int c = 0; c < 8; ++c) {
        const int cur = c & 1;
        const int nxt = cur ^ 1;

        float4 xg[4];                    // next chunk, issued early
        if (c < 7) {
            #pragma unroll
            for (int i = 0; i < 4; ++i)
                xg[i] = *(const float4*)(sp[i] + (c + 1) * 16);
        }

        #pragma unroll
        for (int u = 0; u < 4; ++u) {
            const float4 xv = *(const float4*)(xs + xrb + cur * BUFSTEP + u * 4);
            #pragma unroll
            for (int w = 0; w < 16; ++w) {
                const float* wr = wq + w * EE + c * 16 + u * 4;  // uniform
                acc[w] += xv.x * wr[0] + xv.y * wr[1]
                        + xv.z * wr[2] + xv.w * wr[3];
            }
        }

        if (c < 7) {                     // vmcnt lands here, after the FMAs
            #pragma unroll
            for (int i = 0; i < 4; ++i)
                *(float4*)(xs + dp[i] + nxt * BUFSTEP) = xg[i];
        }
    }

    // ---- 4-way K-split partials -> red (overlays xs: barrier first) ----
    __syncthreads();
    #pragma unroll
    for (int w = 0; w < 16; ++w)
        red[(q * 16 + w) * RSTR + s] = acc[w] * vmask;
    __syncthreads();

    // ---- fused overlap-add: 504 outputs, 256 threads -> 2 iterations ----
    for (int o = tid; o < GPB * 8; o += 256) {
        const int j = o >> 3;            // group offset in block, 0..62
        const int i = o & 7;             // sample within group
        const int g = g0 + j;
        if (g < NGROUP) {
            float v = 0.f;
            #pragma unroll
            for (int qq = 0; qq < 4; ++qq)
                v += red[(qq * 16 + i) * RSTR + (j + 1)]     // est[g][i]
                   + red[(qq * 16 + 8 + i) * RSTR + j];      // est[g-1][8+i]
            out[(size_t)bc * TOUT + g * 8 + i] = v;
        }
    }
}

extern "C" void kernel_launch(void* const* d_in, const int* in_sizes, int n_in,
                              void* d_out, int out_size, void* d_ws, size_t ws_size,
                              hipStream_t stream) {
    const float* dec = (const float*)d_in[0];   // [8,2,3999,512] fp32
    const float* wgt = (const float*)d_in[1];   // [16,512] fp32
    float* out = (float*)d_out;                 // [8,2,32000] fp32

    decoder_kernel<<<dim3(1024), dim3(256), 0, stream>>>(dec, wgt, out);
}